// Round 1
// baseline (132.540 us; speedup 1.0000x reference)
//
#include <hip/hip_runtime.h>
#include <hip/hip_bf16.h>
#include <stdint.h>

// Shapes: B=8, T=2048, E=1024, H=64
// wei[t][s] = k[t]·q[s] * 0.125  (k plays "query", q plays "key"), causal s<=t
// log2(e)*0.125 folded into Wk so softmax uses exp2 directly.

typedef __attribute__((ext_vector_type(4))) float f32x4;
typedef __attribute__((ext_vector_type(4))) short s16x4;
typedef __attribute__((ext_vector_type(8))) short s16x8;
typedef __attribute__((ext_vector_type(2))) unsigned int u32x2;

__device__ __forceinline__ unsigned bf16pack(float a, float b){
    unsigned ua = __builtin_bit_cast(unsigned, a);
    unsigned ub = __builtin_bit_cast(unsigned, b);
    return ((ua + 0x8000u) >> 16) | ((ub + 0x8000u) & 0xffff0000u);
}
__device__ __forceinline__ unsigned short bf16one(float a){
    return (unsigned short)((__builtin_bit_cast(unsigned, a) + 0x8000u) >> 16);
}

// ---------------- W prep: WT[w][n][k] bf16, w=0 scaled by 0.125*log2e ----------------
__global__ __launch_bounds__(256) void wprep_kernel(const float* __restrict__ Wk,
                                                    const float* __restrict__ Wq,
                                                    const float* __restrict__ Wv,
                                                    unsigned short* __restrict__ WT){
    __shared__ float lw[1024][8];
    int w = blockIdx.x, n0 = blockIdx.y * 8, tid = threadIdx.x;
    const float* src = (w == 0) ? Wk : (w == 1) ? Wq : Wv;
    float scale = (w == 0) ? 0.18033688011112042f : 1.0f;  // 0.125 * log2(e)
    for (int it = 0; it < 8; ++it){
        int idx = it * 256 + tid;
        int k = idx >> 1, half = idx & 1;
        f32x4 v = *(const f32x4*)(src + k * 64 + n0 + half * 4);
        *(f32x4*)&lw[k][half * 4] = v;
    }
    __syncthreads();
    int n = tid >> 5, kc = (tid & 31) * 32;
    unsigned short* dst = WT + (size_t)((w * 64 + n0 + n) * 1024 + kc);
    #pragma unroll
    for (int c = 0; c < 4; c++){
        s16x8 v;
        #pragma unroll
        for (int e = 0; e < 8; e++)
            v[e] = (short)bf16one(lw[kc + c * 8 + e][n] * scale);
        *(s16x8*)(dst + c * 8) = v;
    }
}

// ---------------- Projections: kb=(x@Wk)*fold, qb=x@Wq row-major; vT transposed ----------------
__global__ __launch_bounds__(128) void proj_kernel(const float* __restrict__ x,
                                                   const unsigned short* __restrict__ WT,
                                                   unsigned short* __restrict__ kb,
                                                   unsigned short* __restrict__ qb,
                                                   unsigned short* __restrict__ vT){
    __shared__ unsigned short smem[32 * 200];  // A-stage [32][72] reused as out-tile [32][200]
    int tid = threadIdx.x; int l = tid & 63; int wv = tid >> 6;
    int lr = l & 15, lg = l >> 4;
    int m0 = blockIdx.x * 32; int b = m0 >> 11; int t0 = m0 & 2047;
    const float* xp = x + (size_t)m0 * 1024;
    f32x4 acc[2][6] = {};
    int sr = tid >> 2, sc = (tid & 3) * 16;
    for (int k0 = 0; k0 < 1024; k0 += 64){
        const float* g = xp + sr * 1024 + k0 + sc;
        f32x4 va = *(const f32x4*)(g);
        f32x4 vb = *(const f32x4*)(g + 4);
        f32x4 vc = *(const f32x4*)(g + 8);
        f32x4 vd = *(const f32x4*)(g + 12);
        __syncthreads();  // previous iteration's frag reads done
        uint4 w0 = make_uint4(bf16pack(va[0], va[1]), bf16pack(va[2], va[3]),
                              bf16pack(vb[0], vb[1]), bf16pack(vb[2], vb[3]));
        uint4 w1 = make_uint4(bf16pack(vc[0], vc[1]), bf16pack(vc[2], vc[3]),
                              bf16pack(vd[0], vd[1]), bf16pack(vd[2], vd[3]));
        *(uint4*)(smem + sr * 72 + sc)     = w0;
        *(uint4*)(smem + sr * 72 + sc + 8) = w1;
        __syncthreads();
        s16x8 af[2][2];
        #pragma unroll
        for (int m = 0; m < 2; m++){
            const unsigned short* ap = smem + (m * 16 + lr) * 72 + lg * 8;
            af[m][0] = *(const s16x8*)(ap);
            af[m][1] = *(const s16x8*)(ap + 32);
        }
        #pragma unroll
        for (int nn = 0; nn < 6; nn++){
            int nt = wv * 6 + nn;
            const unsigned short* bp = WT + (size_t)(((nt >> 2) * 64 + (nt & 3) * 16 + lr) * 1024 + k0 + lg * 8);
            s16x8 b0 = *(const s16x8*)(bp);
            s16x8 b1 = *(const s16x8*)(bp + 32);
            #pragma unroll
            for (int m = 0; m < 2; m++){
                acc[m][nn] = __builtin_amdgcn_mfma_f32_16x16x32_bf16(af[m][0], b0, acc[m][nn], 0, 0, 0);
                acc[m][nn] = __builtin_amdgcn_mfma_f32_16x16x32_bf16(af[m][1], b1, acc[m][nn], 0, 0, 0);
            }
        }
    }
    __syncthreads();
    // acc -> LDS out tile [32][200] bf16 (cols 0..63 k, 64..127 q, 128..191 v)
    #pragma unroll
    for (int m = 0; m < 2; m++){
        #pragma unroll
        for (int nn = 0; nn < 6; nn++){
            int nt = wv * 6 + nn;
            int row = m * 16 + lg * 4;
            int col = nt * 16 + lr;
            #pragma unroll
            for (int r = 0; r < 4; r++)
                smem[(row + r) * 200 + col] = bf16one(acc[m][nn][r]);
        }
    }
    __syncthreads();
    {
        int r2 = tid >> 2, c2 = (tid & 3) * 32;
        unsigned short* base = (c2 < 64)
            ? (kb + (size_t)(b * 2048 + t0 + r2) * 64 + c2)
            : (qb + (size_t)(b * 2048 + t0 + r2) * 64 + (c2 - 64));
        const unsigned short* srow = smem + r2 * 200 + c2;
        #pragma unroll
        for (int c = 0; c < 4; c++)
            *(s16x8*)(base + c * 8) = *(const s16x8*)(srow + c * 8);
        int h = tid >> 1, tc = (tid & 1) * 16;
        unsigned short* vdst = vT + (size_t)(b * 64 + h) * 2048 + t0 + tc;
        #pragma unroll
        for (int c = 0; c < 2; c++){
            s16x8 vv;
            #pragma unroll
            for (int e = 0; e < 8; e++)
                vv[e] = smem[(tc + c * 8 + e) * 200 + 128 + h];
            *(s16x8*)(vdst + c * 8) = vv;
        }
    }
}

// ---------------- Flash attention: 1024 independent waves, one 16-row t-tile each ----------------
__global__ __launch_bounds__(128) void attn_kernel(const unsigned short* __restrict__ kb,
                                                   const unsigned short* __restrict__ qb,
                                                   const unsigned short* __restrict__ vT,
                                                   float* __restrict__ out){
    int tid = threadIdx.x; int l = tid & 63; int wv = tid >> 6;
    int lr = l & 15, lg = l >> 4;
    int b = blockIdx.y;
    int j = 127 - (blockIdx.x * 2 + wv);  // heavy tiles first
    int t0 = j * 16;
    const unsigned short* fqp = kb + (size_t)(b * 2048 + t0 + lr) * 64 + lg * 8;
    s16x8 fq0 = *(const s16x8*)(fqp);
    s16x8 fq1 = *(const s16x8*)(fqp + 32);
    f32x4 acc[4] = {};
    float mrun = -3.0e38f, lrun = 0.0f;
    int nkv = (j >> 2) + 1;
    const unsigned short* qbb = qb + (size_t)b * 2048 * 64;
    const unsigned short* vbb = vT + (size_t)b * 64 * 2048;
    for (int it = 0; it < nkv; ++it){
        int s0 = it * 64;
        s16x8 fk[4][2];
        #pragma unroll
        for (int n = 0; n < 4; n++){
            const unsigned short* kp = qbb + (size_t)(s0 + n * 16 + lr) * 64 + lg * 8;
            fk[n][0] = *(const s16x8*)(kp);
            fk[n][1] = *(const s16x8*)(kp + 32);
        }
        s16x4 fv[4][4];
        #pragma unroll
        for (int h16 = 0; h16 < 4; h16++){
            const unsigned short* vp = vbb + (size_t)(h16 * 16 + lr) * 2048 + s0 + lg * 4;
            #pragma unroll
            for (int n = 0; n < 4; n++)
                fv[h16][n] = *(const s16x4*)(vp + n * 16);
        }
        // S^T tile: C[s][t] = sum_d q[s][d] * k[t][d]  (A = q rows, B = k rows)
        f32x4 Cs[4];
        #pragma unroll
        for (int n = 0; n < 4; n++){
            f32x4 z = {};
            z     = __builtin_amdgcn_mfma_f32_16x16x32_bf16(fk[n][0], fq0, z, 0, 0, 0);
            Cs[n] = __builtin_amdgcn_mfma_f32_16x16x32_bf16(fk[n][1], fq1, z, 0, 0, 0);
        }
        if (it == nkv - 1){  // only the last KV tile straddles the diagonal
            int tg = t0 + lr;
            #pragma unroll
            for (int n = 0; n < 4; n++){
                int sg = s0 + n * 16 + lg * 4;
                #pragma unroll
                for (int r = 0; r < 4; r++)
                    if (sg + r > tg) Cs[n][r] = -3.0e38f;
            }
        }
        // online softmax over s for each t = lr (stats colocated with Cs cols)
        float pm = -3.0e38f;
        #pragma unroll
        for (int n = 0; n < 4; n++)
            #pragma unroll
            for (int r = 0; r < 4; r++) pm = fmaxf(pm, Cs[n][r]);
        pm = fmaxf(pm, __shfl_xor(pm, 16));
        pm = fmaxf(pm, __shfl_xor(pm, 32));
        float mnew = fmaxf(mrun, pm);
        float scl = exp2f(mrun - mnew);
        float p[4][4]; float ps = 0.0f;
        #pragma unroll
        for (int n = 0; n < 4; n++)
            #pragma unroll
            for (int r = 0; r < 4; r++){ float e = exp2f(Cs[n][r] - mnew); p[n][r] = e; ps += e; }
        ps += __shfl_xor(ps, 16);
        ps += __shfl_xor(ps, 32);
        lrun = lrun * scl + ps;
        mrun = mnew;
        #pragma unroll
        for (int h16 = 0; h16 < 4; h16++) acc[h16] *= scl;
        // P^T regs are exactly the B-fragment of 16x16x16 bf16 MFMA
        s16x4 pb[4];
        #pragma unroll
        for (int n = 0; n < 4; n++){
            u32x2 t; t[0] = bf16pack(p[n][0], p[n][1]); t[1] = bf16pack(p[n][2], p[n][3]);
            pb[n] = __builtin_bit_cast(s16x4, t);
        }
        // out^T tile: C[h][t] += sum_s V^T[h][s] * P^T[s][t]
        #pragma unroll
        for (int h16 = 0; h16 < 4; h16++)
            #pragma unroll
            for (int n = 0; n < 4; n++)
                acc[h16] = __builtin_amdgcn_mfma_f32_16x16x16bf16_1k(fv[h16][n], pb[n], acc[h16], 0, 0, 0);
    }
    float inv = 1.0f / lrun;
    #pragma unroll
    for (int h16 = 0; h16 < 4; h16++){
        f32x4 o = acc[h16] * inv;
        *(f32x4*)(out + (size_t)(b * 2048 + t0 + lr) * 64 + h16 * 16 + lg * 4) = o;
    }
}

extern "C" void kernel_launch(void* const* d_in, const int* in_sizes, int n_in,
                              void* d_out, int out_size, void* d_ws, size_t ws_size,
                              hipStream_t stream) {
    const float* x  = (const float*)d_in[0];
    const float* Wk = (const float*)d_in[1];
    const float* Wq = (const float*)d_in[2];
    const float* Wv = (const float*)d_in[3];
    float* out = (float*)d_out;
    char* ws = (char*)d_ws;
    if (ws_size < (size_t)7 * 1024 * 1024) return;
    unsigned short* WT = (unsigned short*)(ws);              // 384 KB
    unsigned short* kb = (unsigned short*)(ws + (1u << 20)); // 2 MB  (k * 0.125*log2e)
    unsigned short* qb = (unsigned short*)(ws + (3u << 20)); // 2 MB
    unsigned short* vT = (unsigned short*)(ws + (5u << 20)); // 2 MB  ([b][h][t])
    hipLaunchKernelGGL(wprep_kernel, dim3(3, 8), dim3(256), 0, stream, Wk, Wq, Wv, WT);
    hipLaunchKernelGGL(proj_kernel, dim3(512), dim3(128), 0, stream, x, WT, kb, qb, vT);
    hipLaunchKernelGGL(attn_kernel, dim3(64, 8), dim3(128), 0, stream, kb, qb, vT, out);
}

// Round 2
// 119.341 us; speedup vs baseline: 1.1106x; 1.1106x over previous
//
#include <hip/hip_runtime.h>
#include <hip/hip_bf16.h>
#include <stdint.h>

// Shapes: B=8, T=2048, E=1024, H=64
// wei[t][s] = k[t]·q[s] * 0.125  (k plays "query", q plays "key"), causal s<=t
// log2(e)*0.125 folded into Wk so softmax uses exp2 directly.

typedef __attribute__((ext_vector_type(4))) float f32x4;
typedef __attribute__((ext_vector_type(4))) short s16x4;
typedef __attribute__((ext_vector_type(8))) short s16x8;
typedef __attribute__((ext_vector_type(2))) unsigned int u32x2;
typedef __attribute__((ext_vector_type(4))) unsigned int u32x4;

__device__ __forceinline__ unsigned bf16pack(float a, float b){
    unsigned ua = __builtin_bit_cast(unsigned, a);
    unsigned ub = __builtin_bit_cast(unsigned, b);
    return ((ua + 0x8000u) >> 16) | ((ub + 0x8000u) & 0xffff0000u);
}
__device__ __forceinline__ unsigned short bf16one(float a){
    return (unsigned short)((__builtin_bit_cast(unsigned, a) + 0x8000u) >> 16);
}

// ---------------- W prep: WT[w][n][k] bf16, w=0 scaled by 0.125*log2e ----------------
__global__ __launch_bounds__(256) void wprep_kernel(const float* __restrict__ Wk,
                                                    const float* __restrict__ Wq,
                                                    const float* __restrict__ Wv,
                                                    unsigned short* __restrict__ WT){
    __shared__ float lw[1024][8];
    int w = blockIdx.x, n0 = blockIdx.y * 8, tid = threadIdx.x;
    const float* src = (w == 0) ? Wk : (w == 1) ? Wq : Wv;
    float scale = (w == 0) ? 0.18033688011112042f : 1.0f;  // 0.125 * log2(e)
    for (int it = 0; it < 8; ++it){
        int idx = it * 256 + tid;
        int k = idx >> 1, half = idx & 1;
        f32x4 v = *(const f32x4*)(src + k * 64 + n0 + half * 4);
        *(f32x4*)&lw[k][half * 4] = v;
    }
    __syncthreads();
    int n = tid >> 5, kc = (tid & 31) * 32;
    unsigned short* dst = WT + (size_t)((w * 64 + n0 + n) * 1024 + kc);
    #pragma unroll
    for (int c = 0; c < 4; c++){
        s16x8 v;
        #pragma unroll
        for (int e = 0; e < 8; e++)
            v[e] = (short)bf16one(lw[kc + c * 8 + e][n] * scale);
        *(s16x8*)(dst + c * 8) = v;
    }
}

// ---------------- Projections v2: no K-loop LDS, direct A-fragment loads + prefetch ----------------
// block = 256 thr = 4 waves: wave = (msub = wv>>1, half = wv&1); 32 rows/block, 512 blocks.
__global__ __launch_bounds__(256, 2) void proj_kernel(const float* __restrict__ x,
                                                      const unsigned short* __restrict__ WT,
                                                      unsigned short* __restrict__ kb,
                                                      unsigned short* __restrict__ qb,
                                                      unsigned short* __restrict__ vT){
    __shared__ unsigned short smem[32 * 200];
    int tid = threadIdx.x; int l = tid & 63; int wv = tid >> 6;
    int lr = l & 15, lg = l >> 4;
    int msub = wv >> 1, half = wv & 1;
    int row0 = blockIdx.x * 32;
    int b = row0 >> 11; int t0 = row0 & 2047;
    const float* ga = x + (size_t)(row0 + msub * 16 + lr) * 1024 + lg * 8;
    f32x4 acc[6] = {};
    f32x4 a0 = *(const f32x4*)(ga);
    f32x4 a1 = *(const f32x4*)(ga + 4);
    f32x4 a2 = *(const f32x4*)(ga + 32);
    f32x4 a3 = *(const f32x4*)(ga + 36);
    for (int k0 = 0; k0 < 1024; k0 += 64){
        // prefetch next K-chunk of A
        f32x4 n0, n1, n2, n3;
        if (k0 + 64 < 1024){
            const float* gn = ga + k0 + 64;
            n0 = *(const f32x4*)(gn);
            n1 = *(const f32x4*)(gn + 4);
            n2 = *(const f32x4*)(gn + 32);
            n3 = *(const f32x4*)(gn + 36);
        }
        u32x4 p0, p1;
        p0[0] = bf16pack(a0[0], a0[1]); p0[1] = bf16pack(a0[2], a0[3]);
        p0[2] = bf16pack(a1[0], a1[1]); p0[3] = bf16pack(a1[2], a1[3]);
        p1[0] = bf16pack(a2[0], a2[1]); p1[1] = bf16pack(a2[2], a2[3]);
        p1[2] = bf16pack(a3[0], a3[1]); p1[3] = bf16pack(a3[2], a3[3]);
        s16x8 af0 = __builtin_bit_cast(s16x8, p0);
        s16x8 af1 = __builtin_bit_cast(s16x8, p1);
        #pragma unroll
        for (int nn = 0; nn < 6; nn++){
            int nt = half * 6 + nn;
            const unsigned short* bp = WT + (size_t)(((nt >> 2) * 64 + (nt & 3) * 16 + lr)) * 1024 + k0 + lg * 8;
            s16x8 b0 = *(const s16x8*)(bp);
            s16x8 b1 = *(const s16x8*)(bp + 32);
            acc[nn] = __builtin_amdgcn_mfma_f32_16x16x32_bf16(af0, b0, acc[nn], 0, 0, 0);
            acc[nn] = __builtin_amdgcn_mfma_f32_16x16x32_bf16(af1, b1, acc[nn], 0, 0, 0);
        }
        a0 = n0; a1 = n1; a2 = n2; a3 = n3;
    }
    // epilogue: bounce through LDS for vectorized / transposed stores
    #pragma unroll
    for (int nn = 0; nn < 6; nn++){
        int nt = half * 6 + nn;
        int col = nt * 16 + lr;
        int row = msub * 16 + lg * 4;
        #pragma unroll
        for (int r = 0; r < 4; r++)
            smem[(row + r) * 200 + col] = bf16one(acc[nn][r]);
    }
    __syncthreads();
    {
        int r2 = tid >> 3, c2 = (tid & 7) * 16;  // 32 rows x 128 cols (k|q)
        unsigned short* base = (c2 < 64)
            ? (kb + (size_t)(b * 2048 + t0 + r2) * 64 + c2)
            : (qb + (size_t)(b * 2048 + t0 + r2) * 64 + (c2 - 64));
        const unsigned short* srow = smem + r2 * 200 + c2;
        *(s16x8*)(base)     = *(const s16x8*)(srow);
        *(s16x8*)(base + 8) = *(const s16x8*)(srow + 8);
        int h = tid >> 2, tc = (tid & 3) * 8;     // v transpose: 64 h x 32 t
        s16x8 vv;
        #pragma unroll
        for (int e = 0; e < 8; e++)
            vv[e] = smem[(tc + e) * 200 + 128 + h];
        *(s16x8*)(vT + (size_t)(b * 64 + h) * 2048 + t0 + tc) = vv;
    }
}

// ---------------- Flash attention v2: 2-way s-split, paired tiles, reg double-buffer ----------------
// block = 256 thr = 4 waves: pair = wv>>1 (tile 127-bx / bx), strip = wv&1.
__global__ __launch_bounds__(256, 2) void attn_kernel(const unsigned short* __restrict__ kb,
                                                      const unsigned short* __restrict__ qb,
                                                      const unsigned short* __restrict__ vT,
                                                      float* __restrict__ out){
    __shared__ float sacc[2][16][68];
    __shared__ float sml[2][16][2];
    int tid = threadIdx.x; int l = tid & 63; int wv = tid >> 6;
    int lr = l & 15, lg = l >> 4;
    int b = blockIdx.y;
    int pair = wv >> 1, strip = wv & 1;
    int j = (pair == 0) ? (127 - blockIdx.x) : blockIdx.x;
    int t0 = j * 16;
    const unsigned short* fqp = kb + (size_t)(b * 2048 + t0 + lr) * 64 + lg * 8;
    s16x8 fq0 = *(const s16x8*)(fqp);
    s16x8 fq1 = *(const s16x8*)(fqp + 32);
    f32x4 acc[4] = {};
    float mrun = -3.0e38f, lrun = 0.0f;
    int nkv = (j >> 2) + 1;
    const unsigned short* qbb = qb + (size_t)b * 2048 * 64;
    const unsigned short* vbb = vT + (size_t)b * 64 * 2048;

    s16x8 fk[4][2]; s16x4 fv[4][4];
    int idx = strip;
    if (idx < nkv){
        int s0 = idx * 64;
        #pragma unroll
        for (int n = 0; n < 4; n++){
            const unsigned short* kp = qbb + (size_t)(s0 + n * 16 + lr) * 64 + lg * 8;
            fk[n][0] = *(const s16x8*)(kp);
            fk[n][1] = *(const s16x8*)(kp + 32);
        }
        #pragma unroll
        for (int h16 = 0; h16 < 4; h16++){
            const unsigned short* vp = vbb + (size_t)(h16 * 16 + lr) * 2048 + s0 + lg * 4;
            #pragma unroll
            for (int n = 0; n < 4; n++)
                fv[h16][n] = *(const s16x4*)(vp + n * 16);
        }
    }
    for (; idx < nkv; idx += 2){
        // prefetch next strip tile
        s16x8 nk[4][2]; s16x4 nv[4][4];
        int nidx = idx + 2;
        if (nidx < nkv){
            int s0n = nidx * 64;
            #pragma unroll
            for (int n = 0; n < 4; n++){
                const unsigned short* kp = qbb + (size_t)(s0n + n * 16 + lr) * 64 + lg * 8;
                nk[n][0] = *(const s16x8*)(kp);
                nk[n][1] = *(const s16x8*)(kp + 32);
            }
            #pragma unroll
            for (int h16 = 0; h16 < 4; h16++){
                const unsigned short* vp = vbb + (size_t)(h16 * 16 + lr) * 2048 + s0n + lg * 4;
                #pragma unroll
                for (int n = 0; n < 4; n++)
                    nv[h16][n] = *(const s16x4*)(vp + n * 16);
            }
        }
        int s0 = idx * 64;
        // S^T tile: C[s][t] = sum_d q[s][d] * k[t][d]
        f32x4 Cs[4];
        #pragma unroll
        for (int n = 0; n < 4; n++){
            f32x4 z = {};
            z     = __builtin_amdgcn_mfma_f32_16x16x32_bf16(fk[n][0], fq0, z, 0, 0, 0);
            Cs[n] = __builtin_amdgcn_mfma_f32_16x16x32_bf16(fk[n][1], fq1, z, 0, 0, 0);
        }
        if (idx == nkv - 1){  // diagonal tile
            int tg = t0 + lr;
            #pragma unroll
            for (int n = 0; n < 4; n++){
                int sg = s0 + n * 16 + lg * 4;
                #pragma unroll
                for (int r = 0; r < 4; r++)
                    if (sg + r > tg) Cs[n][r] = -3.0e38f;
            }
        }
        float pm = -3.0e38f;
        #pragma unroll
        for (int n = 0; n < 4; n++)
            #pragma unroll
            for (int r = 0; r < 4; r++) pm = fmaxf(pm, Cs[n][r]);
        pm = fmaxf(pm, __shfl_xor(pm, 16));
        pm = fmaxf(pm, __shfl_xor(pm, 32));
        float mnew = fmaxf(mrun, pm);
        float scl = exp2f(mrun - mnew);
        float p[4][4]; float ps = 0.0f;
        #pragma unroll
        for (int n = 0; n < 4; n++)
            #pragma unroll
            for (int r = 0; r < 4; r++){ float e = exp2f(Cs[n][r] - mnew); p[n][r] = e; ps += e; }
        ps += __shfl_xor(ps, 16);
        ps += __shfl_xor(ps, 32);
        lrun = lrun * scl + ps;
        mrun = mnew;
        #pragma unroll
        for (int h16 = 0; h16 < 4; h16++) acc[h16] *= scl;
        s16x4 pb[4];
        #pragma unroll
        for (int n = 0; n < 4; n++){
            u32x2 t; t[0] = bf16pack(p[n][0], p[n][1]); t[1] = bf16pack(p[n][2], p[n][3]);
            pb[n] = __builtin_bit_cast(s16x4, t);
        }
        #pragma unroll
        for (int h16 = 0; h16 < 4; h16++)
            #pragma unroll
            for (int n = 0; n < 4; n++)
                acc[h16] = __builtin_amdgcn_mfma_f32_16x16x16bf16_1k(fv[h16][n], pb[n], acc[h16], 0, 0, 0);
        #pragma unroll
        for (int n = 0; n < 4; n++){ fk[n][0] = nk[n][0]; fk[n][1] = nk[n][1]; }
        #pragma unroll
        for (int h16 = 0; h16 < 4; h16++)
            #pragma unroll
            for (int n = 0; n < 4; n++) fv[h16][n] = nv[h16][n];
    }
    // combine the two strips of each pair
    if (strip == 1){
        #pragma unroll
        for (int h16 = 0; h16 < 4; h16++)
            #pragma unroll
            for (int r = 0; r < 4; r++)
                sacc[pair][lr][h16 * 16 + lg * 4 + r] = acc[h16][r];
        if (lg == 0){ sml[pair][lr][0] = mrun; sml[pair][lr][1] = lrun; }
    }
    __syncthreads();
    if (strip == 0){
        float m1 = sml[pair][lr][0], l1 = sml[pair][lr][1];
        float mf = fmaxf(mrun, m1);
        float c0 = exp2f(mrun - mf), c1 = exp2f(m1 - mf);
        float inv = 1.0f / (lrun * c0 + l1 * c1);
        #pragma unroll
        for (int h16 = 0; h16 < 4; h16++){
            f32x4 o;
            #pragma unroll
            for (int r = 0; r < 4; r++)
                o[r] = (acc[h16][r] * c0 + sacc[pair][lr][h16 * 16 + lg * 4 + r] * c1) * inv;
            *(f32x4*)(out + (size_t)(b * 2048 + t0 + lr) * 64 + h16 * 16 + lg * 4) = o;
        }
    }
}

extern "C" void kernel_launch(void* const* d_in, const int* in_sizes, int n_in,
                              void* d_out, int out_size, void* d_ws, size_t ws_size,
                              hipStream_t stream) {
    const float* x  = (const float*)d_in[0];
    const float* Wk = (const float*)d_in[1];
    const float* Wq = (const float*)d_in[2];
    const float* Wv = (const float*)d_in[3];
    float* out = (float*)d_out;
    char* ws = (char*)d_ws;
    if (ws_size < (size_t)7 * 1024 * 1024) return;
    unsigned short* WT = (unsigned short*)(ws);              // 384 KB
    unsigned short* kb = (unsigned short*)(ws + (1u << 20)); // 2 MB  (k * 0.125*log2e)
    unsigned short* qb = (unsigned short*)(ws + (3u << 20)); // 2 MB
    unsigned short* vT = (unsigned short*)(ws + (5u << 20)); // 2 MB  ([b][h][t])
    hipLaunchKernelGGL(wprep_kernel, dim3(3, 8), dim3(256), 0, stream, Wk, Wq, Wv, WT);
    hipLaunchKernelGGL(proj_kernel, dim3(512), dim3(256), 0, stream, x, WT, kb, qb, vT);
    hipLaunchKernelGGL(attn_kernel, dim3(64, 8), dim3(256), 0, stream, kb, qb, vT, out);
}

// Round 4
// 106.058 us; speedup vs baseline: 1.2497x; 1.1252x over previous
//
#include <hip/hip_runtime.h>
#include <hip/hip_bf16.h>
#include <stdint.h>

// Shapes: B=8, T=2048, E=1024, H=64
// wei[t][s] = k[t]·q[s] * 0.125 (k plays "query"), causal s<=t.
// 0.125*log2(e) folded into Wk so softmax uses exp2 directly.

typedef __attribute__((ext_vector_type(4))) float f32x4;
typedef __attribute__((ext_vector_type(4))) short s16x4;
typedef __attribute__((ext_vector_type(8))) short s16x8;
typedef __attribute__((ext_vector_type(2))) unsigned int u32x2;
typedef __attribute__((ext_vector_type(4))) unsigned int u32x4;

__device__ __forceinline__ unsigned bf16pack(float a, float b){
    unsigned ua = __builtin_bit_cast(unsigned, a);
    unsigned ub = __builtin_bit_cast(unsigned, b);
    return ((ua + 0x8000u) >> 16) | ((ub + 0x8000u) & 0xffff0000u);
}
__device__ __forceinline__ unsigned short bf16one(float a){
    return (unsigned short)((__builtin_bit_cast(unsigned, a) + 0x8000u) >> 16);
}

// ---------------- W prep: WT[192][1024] bf16 (rows 0..63 k-scaled, 64..127 q, 128..191 v) ----------
__global__ __launch_bounds__(256) void wprep_kernel(const float* __restrict__ Wk,
                                                    const float* __restrict__ Wq,
                                                    const float* __restrict__ Wv,
                                                    unsigned short* __restrict__ WT){
    __shared__ float lw[1024][8];
    int w = blockIdx.x, n0 = blockIdx.y * 8, tid = threadIdx.x;
    const float* src = (w == 0) ? Wk : (w == 1) ? Wq : Wv;
    float scale = (w == 0) ? 0.18033688011112042f : 1.0f;  // 0.125 * log2(e)
    for (int it = 0; it < 8; ++it){
        int idx = it * 256 + tid;
        int k = idx >> 1, half = idx & 1;
        f32x4 v = *(const f32x4*)(src + k * 64 + n0 + half * 4);
        *(f32x4*)&lw[k][half * 4] = v;
    }
    __syncthreads();
    int n = tid >> 5, kc = (tid & 31) * 32;
    unsigned short* dst = WT + (size_t)((w * 64 + n0 + n) * 1024 + kc);
    #pragma unroll
    for (int c = 0; c < 4; c++){
        s16x8 v;
        #pragma unroll
        for (int e = 0; e < 8; e++)
            v[e] = (short)bf16one(lw[kc + c * 8 + e][n] * scale);
        *(s16x8*)(dst + c * 8) = v;
    }
}

// ---------------- Projections v4: 512 blocks x 256 thr (4 waves), 32-row tiles ----------------
// wave w (0..3): 3 n-tiles (w*3..w*3+2) x 2 m-frags. 2 blocks/CU, one barrier/K-step.
// x staged fp32->bf16 into swizzled LDS [32][64] dbuf; B (WT) direct from L2.
__global__ __launch_bounds__(256, 2) void proj_kernel(const float* __restrict__ x,
                                                      const unsigned short* __restrict__ WT,
                                                      unsigned short* __restrict__ kb,
                                                      unsigned short* __restrict__ qb,
                                                      unsigned short* __restrict__ vP){
    __shared__ unsigned short smem[32 * 200];  // dbuf x-tiles [0..2047],[2048..4095]; out-tile [32][200]
    int tid = threadIdx.x; int l = tid & 63;
    int w = tid >> 6;
    int lr = l & 15, lg = l >> 4;
    int row0 = blockIdx.x * 32;
    int b = row0 >> 11, t0 = row0 & 2047;

    // staging map: thread -> (srow 0..31, schunk 0..7 of 8 floats); swizzle chunk ^= row&7
    int srow = tid >> 3, schunk = tid & 7;
    const float* sg = x + (size_t)(row0 + srow) * 1024 + schunk * 8;
    unsigned short* swr = smem + srow * 64 + ((schunk ^ (srow & 7)) * 8);

    // A ds-read addrs (buf0): row = mf*16+lr, chunk = (kc*4+lg)^(row&7)
    const unsigned short* ard[2][2];
    #pragma unroll
    for (int mf = 0; mf < 2; mf++){
        int ar = mf * 16 + lr;
        #pragma unroll
        for (int kc = 0; kc < 2; kc++)
            ard[mf][kc] = smem + ar * 64 + (((kc * 4 + lg) ^ (ar & 7)) * 8);
    }
    // B global base pointers (3 n-tiles per wave)
    const unsigned short* bp[3];
    #pragma unroll
    for (int nn = 0; nn < 3; nn++)
        bp[nn] = WT + (size_t)((w * 3 + nn) * 16 + lr) * 1024 + lg * 8;

    f32x4 acc[2][3] = {};

    // prologue: stage k0=0 into buf0
    f32x4 xa = *(const f32x4*)(sg);
    f32x4 xb = *(const f32x4*)(sg + 4);
    {
        u32x4 pk;
        pk[0] = bf16pack(xa[0], xa[1]); pk[1] = bf16pack(xa[2], xa[3]);
        pk[2] = bf16pack(xb[0], xb[1]); pk[3] = bf16pack(xb[2], xb[3]);
        *(u32x4*)swr = pk;
    }
    int cur = 0;
    for (int k0 = 0; k0 < 1024; k0 += 64){
        __syncthreads();
        // B loads for this step
        s16x8 bf[3][2];
        #pragma unroll
        for (int nn = 0; nn < 3; nn++){
            bf[nn][0] = *(const s16x8*)(bp[nn] + k0);
            bf[nn][1] = *(const s16x8*)(bp[nn] + k0 + 32);
        }
        // x loads for next step (clamped, unconditional -> no UB, stays hoisted)
        int kn = (k0 + 64 < 1024) ? (k0 + 64) : 960;
        xa = *(const f32x4*)(sg + kn);
        xb = *(const f32x4*)(sg + kn + 4);
        // A fragments from LDS (buffer cur)
        s16x8 af[2][2];
        #pragma unroll
        for (int mf = 0; mf < 2; mf++)
            #pragma unroll
            for (int kc = 0; kc < 2; kc++)
                af[mf][kc] = *(const s16x8*)(ard[mf][kc] + cur * 2048);
        #pragma unroll
        for (int nn = 0; nn < 3; nn++)
            #pragma unroll
            for (int mf = 0; mf < 2; mf++){
                acc[mf][nn] = __builtin_amdgcn_mfma_f32_16x16x32_bf16(af[mf][0], bf[nn][0], acc[mf][nn], 0, 0, 0);
                acc[mf][nn] = __builtin_amdgcn_mfma_f32_16x16x32_bf16(af[mf][1], bf[nn][1], acc[mf][nn], 0, 0, 0);
            }
        // convert + stage-write next buf (last iter redundant; overwritten after barrier)
        {
            u32x4 pk;
            pk[0] = bf16pack(xa[0], xa[1]); pk[1] = bf16pack(xa[2], xa[3]);
            pk[2] = bf16pack(xb[0], xb[1]); pk[3] = bf16pack(xb[2], xb[3]);
            *(u32x4*)(swr + (cur ^ 1) * 2048) = pk;
        }
        cur ^= 1;
    }
    __syncthreads();
    // epilogue: acc -> out tile [32][200] bf16 (cols 0..63 k, 64..127 q, 128..191 v)
    #pragma unroll
    for (int mf = 0; mf < 2; mf++)
        #pragma unroll
        for (int nn = 0; nn < 3; nn++){
            int col = (w * 3 + nn) * 16 + lr;
            int row = mf * 16 + lg * 4;
            #pragma unroll
            for (int r = 0; r < 4; r++)
                smem[(row + r) * 200 + col] = bf16one(acc[mf][nn][r]);
        }
    __syncthreads();
    {
        // k|q rows: 32 rows x 128 cols
        int r2 = tid >> 3, c2 = (tid & 7) * 16;
        const unsigned short* srowp = smem + r2 * 200 + c2;
        unsigned short* dst = (c2 < 64)
            ? kb + (size_t)(b * 2048 + t0 + r2) * 64 + c2
            : qb + (size_t)(b * 2048 + t0 + r2) * 64 + (c2 - 64);
        *(s16x8*)(dst)     = *(const s16x8*)(srowp);
        *(s16x8*)(dst + 8) = *(const s16x8*)(srowp + 8);
        // vP permuted store: slot jj (0..31) holds t-local sl = ((jj&3)|((jj>>3)<<2)) + 16*((jj>>2)&1)
        int h = tid >> 2, q3 = tid & 3;
        s16x8 vv;
        #pragma unroll
        for (int e = 0; e < 8; e++){
            int jj = q3 * 8 + e;
            int bb = (jj >> 2) & 1;
            int aa = (jj & 3) | ((jj >> 3) << 2);
            int sl = aa + 16 * bb;
            vv[e] = smem[sl * 200 + 128 + h];
        }
        *(s16x8*)(vP + (size_t)(b * 64 + h) * 2048 + t0 + q3 * 8) = vv;
    }
}

// ---------------- Flash attention v4: 1024 blocks x 4 waves; wave = s-strip, LDS combine ------------
__global__ __launch_bounds__(256, 4) void attn_kernel(const unsigned short* __restrict__ kb,
                                                      const unsigned short* __restrict__ qb,
                                                      const unsigned short* __restrict__ vP,
                                                      float* __restrict__ out){
    __shared__ float sacc[4][16][72];
    __shared__ float sml[4][16][2];
    int tid = threadIdx.x; int l = tid & 63; int strip = tid >> 6;
    int lr = l & 15, lg = l >> 4;
    int b = blockIdx.y;
    int j = 127 - blockIdx.x;  // heavy tiles first
    int t0 = j * 16;
    const unsigned short* fqp = kb + (size_t)(b * 2048 + t0 + lr) * 64 + lg * 8;
    s16x8 fq0 = *(const s16x8*)(fqp);
    s16x8 fq1 = *(const s16x8*)(fqp + 32);
    const unsigned short* qbb = qb + (size_t)b * 2048 * 64;
    const unsigned short* vbb = vP + (size_t)b * 64 * 2048;
    f32x4 acc[4] = {};
    float mrun = -3.0e38f, lrun = 0.0f;
    int dj = j >> 2;  // diagonal 64-chunk index
    for (int idx = strip; idx <= dj; idx += 4){
        int s0 = idx * 64;
        // k + v fragment loads issue together; QK MFMAs wait only on k (in-order vmcnt),
        // v stays in flight through the softmax.
        s16x8 fk[4][2];
        #pragma unroll
        for (int n = 0; n < 4; n++){
            const unsigned short* kp = qbb + (size_t)(s0 + n * 16 + lr) * 64 + lg * 8;
            fk[n][0] = *(const s16x8*)(kp);
            fk[n][1] = *(const s16x8*)(kp + 32);
        }
        s16x8 fvp[4][2];
        #pragma unroll
        for (int h16 = 0; h16 < 4; h16++)
            #pragma unroll
            for (int n2 = 0; n2 < 2; n2++)
                fvp[h16][n2] = *(const s16x8*)(vbb + (size_t)(h16 * 16 + lr) * 2048 + s0 + n2 * 32 + lg * 8);
        // S^T: C[s][t] = sum_d q[s][d]*k[t][d]
        f32x4 Cs[4];
        #pragma unroll
        for (int n = 0; n < 4; n++){
            f32x4 z = {};
            z     = __builtin_amdgcn_mfma_f32_16x16x32_bf16(fk[n][0], fq0, z, 0, 0, 0);
            Cs[n] = __builtin_amdgcn_mfma_f32_16x16x32_bf16(fk[n][1], fq1, z, 0, 0, 0);
        }
        if (idx == dj){  // diagonal chunk
            int tg = t0 + lr;
            #pragma unroll
            for (int n = 0; n < 4; n++){
                int sg = s0 + n * 16 + lg * 4;
                #pragma unroll
                for (int r = 0; r < 4; r++)
                    if (sg + r > tg) Cs[n][r] = -3.0e38f;
            }
        }
        float pm = -3.0e38f;
        #pragma unroll
        for (int n = 0; n < 4; n++)
            #pragma unroll
            for (int r = 0; r < 4; r++) pm = fmaxf(pm, Cs[n][r]);
        pm = fmaxf(pm, __shfl_xor(pm, 16));
        pm = fmaxf(pm, __shfl_xor(pm, 32));
        float mnew = fmaxf(mrun, pm);
        float scl = exp2f(mrun - mnew);
        float p[4][4]; float ps = 0.0f;
        #pragma unroll
        for (int n = 0; n < 4; n++)
            #pragma unroll
            for (int r = 0; r < 4; r++){ float e = exp2f(Cs[n][r] - mnew); p[n][r] = e; ps += e; }
        ps += __shfl_xor(ps, 16);
        ps += __shfl_xor(ps, 32);
        lrun = lrun * scl + ps;
        mrun = mnew;
        #pragma unroll
        for (int h16 = 0; h16 < 4; h16++) acc[h16] *= scl;
        s16x4 pb[4];
        #pragma unroll
        for (int n = 0; n < 4; n++){
            u32x2 t; t[0] = bf16pack(p[n][0], p[n][1]); t[1] = bf16pack(p[n][2], p[n][3]);
            pb[n] = __builtin_bit_cast(s16x4, t);
        }
        // out^T: C[h][t] += sum_s V^T[h][s] * P^T[s][t]
        #pragma unroll
        for (int h16 = 0; h16 < 4; h16++)
            #pragma unroll
            for (int n2 = 0; n2 < 2; n2++){
                s16x4 flo = __builtin_shufflevector(fvp[h16][n2], fvp[h16][n2], 0, 1, 2, 3);
                s16x4 fhi = __builtin_shufflevector(fvp[h16][n2], fvp[h16][n2], 4, 5, 6, 7);
                acc[h16] = __builtin_amdgcn_mfma_f32_16x16x16bf16_1k(flo, pb[n2 * 2],     acc[h16], 0, 0, 0);
                acc[h16] = __builtin_amdgcn_mfma_f32_16x16x16bf16_1k(fhi, pb[n2 * 2 + 1], acc[h16], 0, 0, 0);
            }
    }
    // write partials (empty strips: mrun=-3e38, lrun=0, acc=0 -> zero weight in combine)
    #pragma unroll
    for (int h16 = 0; h16 < 4; h16++)
        #pragma unroll
        for (int r = 0; r < 4; r++)
            sacc[strip][lr][h16 * 16 + lg * 4 + r] = acc[h16][r];
    if (lg == 0){ sml[strip][lr][0] = mrun; sml[strip][lr][1] = lrun; }
    __syncthreads();
    // combine: thread -> (row = tid>>4, colgroup = (tid&15)*4)
    {
        int row = tid >> 4, cg = (tid & 15) * 4;
        float m0 = sml[0][row][0], m1 = sml[1][row][0], m2 = sml[2][row][0], m3 = sml[3][row][0];
        float mg = fmaxf(fmaxf(m0, m1), fmaxf(m2, m3));
        float w0 = exp2f(m0 - mg), w1 = exp2f(m1 - mg);
        float w2 = exp2f(m2 - mg), w3 = exp2f(m3 - mg);
        float lt = sml[0][row][1] * w0 + sml[1][row][1] * w1 + sml[2][row][1] * w2 + sml[3][row][1] * w3;
        float inv = 1.0f / lt;
        f32x4 o = (*(const f32x4*)&sacc[0][row][cg]) * w0;
        o += (*(const f32x4*)&sacc[1][row][cg]) * w1;
        o += (*(const f32x4*)&sacc[2][row][cg]) * w2;
        o += (*(const f32x4*)&sacc[3][row][cg]) * w3;
        o *= inv;
        *(f32x4*)(out + (size_t)(b * 2048 + t0 + row) * 64 + cg) = o;
    }
}

extern "C" void kernel_launch(void* const* d_in, const int* in_sizes, int n_in,
                              void* d_out, int out_size, void* d_ws, size_t ws_size,
                              hipStream_t stream) {
    const float* x  = (const float*)d_in[0];
    const float* Wk = (const float*)d_in[1];
    const float* Wq = (const float*)d_in[2];
    const float* Wv = (const float*)d_in[3];
    float* out = (float*)d_out;
    char* ws = (char*)d_ws;
    if (ws_size < (size_t)7 * 1024 * 1024) return;
    unsigned short* WT = (unsigned short*)(ws);              // 384 KB
    unsigned short* kb = (unsigned short*)(ws + (1u << 20)); // 2 MB (k * 0.125*log2e)
    unsigned short* qb = (unsigned short*)(ws + (3u << 20)); // 2 MB
    unsigned short* vP = (unsigned short*)(ws + (5u << 20)); // 2 MB ([b][h][t32-permuted])
    hipLaunchKernelGGL(wprep_kernel, dim3(3, 8), dim3(256), 0, stream, Wk, Wq, Wv, WT);
    hipLaunchKernelGGL(proj_kernel, dim3(512), dim3(256), 0, stream, x, WT, kb, qb, vP);
    hipLaunchKernelGGL(attn_kernel, dim3(128, 8), dim3(256), 0, stream, kb, qb, vP, out);
}